// Round 9
// baseline (630.614 us; speedup 1.0000x reference)
//
#include <hip/hip_runtime.h>
#include <math.h>

#define NNODES 50000
#define NEDGES 200000

typedef unsigned short ushort_t;
using frag8 = __attribute__((ext_vector_type(8))) short;   // 8 x bf16
using facc4 = __attribute__((ext_vector_type(4))) float;   // 4 x f32

#define GLL16(g, l) __builtin_amdgcn_global_load_lds(                      \
    (const __attribute__((address_space(1))) void*)(g),                    \
    (__attribute__((address_space(3))) void*)(l), 16, 0, 0)

// ---------- bf16 helpers (bit-level, RNE) ----------
static __device__ __forceinline__ ushort_t f2b(float f) {
  union { float f; unsigned u; } v; v.f = f;
  unsigned r = v.u + 0x7FFFu + ((v.u >> 16) & 1u);
  return (ushort_t)(r >> 16);
}
static __device__ __forceinline__ float b2f(unsigned hi) {
  return __uint_as_float(hi << 16);
}
static __device__ __forceinline__ void unpack8(const int4 v, float* f) {
  f[0] = b2f((unsigned)v.x & 0xFFFFu); f[1] = b2f((unsigned)v.x >> 16);
  f[2] = b2f((unsigned)v.y & 0xFFFFu); f[3] = b2f((unsigned)v.y >> 16);
  f[4] = b2f((unsigned)v.z & 0xFFFFu); f[5] = b2f((unsigned)v.z >> 16);
  f[6] = b2f((unsigned)v.w & 0xFFFFu); f[7] = b2f((unsigned)v.w >> 16);
}
static __device__ __forceinline__ void stf(float* p, float v) { *p = v; }
static __device__ __forceinline__ void stf(ushort_t* p, float v) { *p = f2b(v); }

// ---------- cast x (fp32) -> bf16, 8 elems/thread ----------
__global__ void cast_x(const float* __restrict__ x, ushort_t* __restrict__ xb, int total8) {
  int t = blockIdx.x * 256 + threadIdx.x;
  if (t >= total8) return;
  const float4* p = (const float4*)(x + (size_t)t * 8);
  float4 a = p[0], b = p[1];
  int4 w = make_int4(
      (int)((unsigned)f2b(a.x) | ((unsigned)f2b(a.y) << 16)),
      (int)((unsigned)f2b(a.z) | ((unsigned)f2b(a.w) << 16)),
      (int)((unsigned)f2b(b.x) | ((unsigned)f2b(b.y) << 16)),
      (int)((unsigned)f2b(b.z) | ((unsigned)f2b(b.w) << 16)));
  *(int4*)(xb + (size_t)t * 8) = w;
}

// ---------- weight transpose + cast (L and R into one buffer) ----------
__global__ void wt_prep2(const float* __restrict__ Wl, const float* __restrict__ Wr,
                         ushort_t* __restrict__ WtLR, int K, int Mo) {
  int t = blockIdx.x * 256 + threadIdx.x;
  const int tot = K * Mo;
  if (t >= 2 * tot) return;
  const float* W = (t < tot) ? Wl : Wr;
  int u = (t < tot) ? t : t - tot;
  int c = u / K, k = u - c * K;
  WtLR[t] = f2b(W[(size_t)k * Mo + c]);
}

// ---------- fused MFMA GEMM: [xl|xr][N,Mo](bf16) = A[N,K](bf16) * WtLR + bias ----------
// BK=64, global_load_lds staging, XCD-bijective swizzle, LDS-staged epilogue.
__global__ __launch_bounds__(256) void gemm2_mfma(
    const ushort_t* __restrict__ A, const ushort_t* __restrict__ WtLR,
    const float* __restrict__ bl, const float* __restrict__ br,
    ushort_t* __restrict__ xlb, ushort_t* __restrict__ xrb,
    int N, int K, int Mo, int ncb) {
  // union: A planes [8][129][8] (16512B) + B planes (16512B)  /  Cl [64][140] (17920B)
  __shared__ __align__(16) char smem[33024];
  auto Al = reinterpret_cast<ushort_t(*)[129][8]>(smem);
  auto Bl = reinterpret_cast<ushort_t(*)[129][8]>(smem + 16512);
  auto Cl = reinterpret_cast<ushort_t(*)[140]>(smem);
  char* ldsA = (char*)smem;
  char* ldsB = (char*)smem + 16512;

  // bijective XCD-chunked swizzle
  const int nwg = gridDim.x;
  const int q = nwg >> 3, r = nwg & 7;
  const int xcd = blockIdx.x & 7, pos = blockIdx.x >> 3;
  const int orig = (xcd < r ? xcd * (q + 1) : r * (q + 1) + (xcd - r) * q) + pos;
  const int rp = orig / ncb, cb = orig - rp * ncb;
  const int brow = rp * 128;
  const int bcol = cb * 128;                 // within [0, 2*Mo)

  const int tid = threadIdx.x;
  const int w = tid >> 6, lane = tid & 63;
  const int wr = w >> 1, wc = w & 1;         // 2x2 waves
  const int l15 = lane & 15, l4 = lane >> 4;

  facc4 acc[4][4] = {};

  // per-lane source rows (clamped for OOB; results discarded on write)
  int ra0 = brow + lane;        if (ra0 > N - 1) ra0 = N - 1;
  int ra1 = brow + 64 + lane;   if (ra1 > N - 1) ra1 = N - 1;
  const ushort_t* pA0 = A + (size_t)ra0 * K;
  const ushort_t* pA1 = A + (size_t)ra1 * K;
  const ushort_t* pB0 = WtLR + (size_t)(bcol + lane) * K;
  const ushort_t* pB1 = WtLR + (size_t)(bcol + 64 + lane) * K;

  for (int k0 = 0; k0 < K; k0 += 64) {
    // ---- async stage: 4 A chunks + 4 B chunks per wave (1KB each) ----
    #pragma unroll
    for (int c = 0; c < 4; ++c) {
      const int kb = 2 * w + (c >> 1);       // kb plane 0..7
      const int rh = c & 1;                  // row half
      const int ko = k0 + kb * 8;
      GLL16((rh ? pA1 : pA0) + ko, ldsA + kb * 2064 + rh * 1024);
      GLL16((rh ? pB1 : pB0) + ko, ldsB + kb * 2064 + rh * 1024);
    }
    __syncthreads();
    // ---- compute: 2 sub-steps of K=32 ----
    #pragma unroll
    for (int kk = 0; kk < 2; ++kk) {
      frag8 af[4], bfg[4];
      #pragma unroll
      for (int i = 0; i < 4; ++i)
        af[i] = *(const frag8*)&Al[kk * 4 + l4][wr * 64 + i * 16 + l15][0];
      #pragma unroll
      for (int j = 0; j < 4; ++j)
        bfg[j] = *(const frag8*)&Bl[kk * 4 + l4][wc * 64 + j * 16 + l15][0];
      #pragma unroll
      for (int i = 0; i < 4; ++i)
        #pragma unroll
        for (int j = 0; j < 4; ++j)
          acc[i][j] = __builtin_amdgcn_mfma_f32_16x16x32_bf16(af[i], bfg[j], acc[i][j], 0, 0, 0);
    }
    __syncthreads();
  }

  // ---- epilogue: two 64-row halves through LDS, coalesced int4 writeout ----
  #pragma unroll
  for (int half = 0; half < 2; ++half) {
    if (wr == half) {
      #pragma unroll
      for (int j = 0; j < 4; ++j) {
        const int lcol = wc * 64 + j * 16 + l15;
        const int col2 = bcol + lcol;
        const float bv = (col2 < Mo) ? bl[col2] : br[col2 - Mo];
        #pragma unroll
        for (int i = 0; i < 4; ++i) {
          const int lrow = i * 16 + l4 * 4;
          #pragma unroll
          for (int rr = 0; rr < 4; ++rr)
            Cl[lrow + rr][lcol] = f2b(acc[i][j][rr] + bv);
        }
      }
    }
    __syncthreads();
    {
      const int row = tid >> 2, cq = tid & 3;
      const int grow = brow + half * 64 + row;
      if (grow < N) {
        const int colb = cq * 32;
        const int col2 = bcol + colb;          // side uniform per 32-col chunk
        const bool isL = col2 < Mo;
        ushort_t* dst = (isL ? xlb : xrb) + (size_t)grow * Mo + (isL ? col2 : col2 - Mo);
        #pragma unroll
        for (int k = 0; k < 4; ++k) {
          int4 v = *(const int4*)&Cl[row][colb + k * 8];
          *(int4*)(dst + k * 8) = v;
        }
      }
    }
    __syncthreads();
  }
}

// ---------- CSR build (by dst) ----------
__global__ void csr_zero(int* __restrict__ deg) {
  int t = blockIdx.x * blockDim.x + threadIdx.x;
  if (t < NNODES) deg[t] = 0;
}
__global__ void csr_hist(const int* __restrict__ ei, int* __restrict__ deg) {
  int e = blockIdx.x * blockDim.x + threadIdx.x;
  if (e >= NEDGES) return;
  atomicAdd(&deg[ei[NEDGES + e]], 1);
}

#define SCAN_TPB 256
#define SCAN_EPT 4
#define SCAN_CHUNK (SCAN_TPB * SCAN_EPT)                       // 1024
#define SCAN_BLK ((NNODES + SCAN_CHUNK - 1) / SCAN_CHUNK)      // 49

__global__ __launch_bounds__(SCAN_TPB) void scan_k1(const int* __restrict__ deg,
                                                    int* __restrict__ bsum) {
  __shared__ int sd[SCAN_TPB];
  const int tid = threadIdx.x;
  const int tbase = blockIdx.x * SCAN_CHUNK + tid * SCAN_EPT;
  int s = 0;
  #pragma unroll
  for (int j = 0; j < SCAN_EPT; ++j) {
    int idx = tbase + j;
    if (idx < NNODES) s += deg[idx];
  }
  sd[tid] = s;
  __syncthreads();
  for (int d = SCAN_TPB / 2; d > 0; d >>= 1) {
    if (tid < d) sd[tid] += sd[tid + d];
    __syncthreads();
  }
  if (tid == 0) bsum[blockIdx.x] = sd[0];
}

__global__ __launch_bounds__(64) void scan_k2(const int* __restrict__ bsum,
                                              int* __restrict__ bpref,
                                              int* __restrict__ off) {
  __shared__ int sd[64];
  const int tid = threadIdx.x;
  sd[tid] = (tid < SCAN_BLK) ? bsum[tid] : 0;
  __syncthreads();
  for (int d = 1; d < 64; d <<= 1) {
    int t = (tid >= d) ? sd[tid - d] : 0;
    __syncthreads();
    sd[tid] += t;
    __syncthreads();
  }
  if (tid < SCAN_BLK) bpref[tid] = (tid == 0) ? 0 : sd[tid - 1];
  if (tid == 0) off[NNODES] = NEDGES;
}

__global__ __launch_bounds__(SCAN_TPB) void scan_k3(const int* __restrict__ deg,
                                                    const int* __restrict__ bpref,
                                                    int* __restrict__ off,
                                                    int* __restrict__ pos) {
  __shared__ int sd[SCAN_TPB];
  const int tid = threadIdx.x;
  const int tbase = blockIdx.x * SCAN_CHUNK + tid * SCAN_EPT;
  int v[SCAN_EPT];
  int s = 0;
  #pragma unroll
  for (int j = 0; j < SCAN_EPT; ++j) {
    int idx = tbase + j;
    v[j] = (idx < NNODES) ? deg[idx] : 0;
    s += v[j];
  }
  sd[tid] = s;
  __syncthreads();
  for (int d = 1; d < SCAN_TPB; d <<= 1) {
    int t = (tid >= d) ? sd[tid - d] : 0;
    __syncthreads();
    sd[tid] += t;
    __syncthreads();
  }
  int run = bpref[blockIdx.x] + ((tid == 0) ? 0 : sd[tid - 1]);
  #pragma unroll
  for (int j = 0; j < SCAN_EPT; ++j) {
    int idx = tbase + j;
    if (idx < NNODES) { off[idx] = run; pos[idx] = run; run += v[j]; }
  }
}

__global__ void csr_fill(const int* __restrict__ ei, int* __restrict__ pos,
                         int* __restrict__ eids) {
  int e = blockIdx.x * blockDim.x + threadIdx.x;
  if (e >= NEDGES) return;
  int p = atomicAdd(&pos[ei[NEDGES + e]], 1);
  eids[p] = e;
}

// ---------- fused attention + online-softmax aggregation, one wave/node ----------
template<int H, int C, bool ELU, typename TO>
__global__ __launch_bounds__(256) void csr_fused(
    const int* __restrict__ off, const int* __restrict__ eids,
    const int* __restrict__ ei, const ushort_t* __restrict__ xl,
    const ushort_t* __restrict__ xr, const float* __restrict__ att,
    const float* __restrict__ bias, TO* __restrict__ out) {
  constexpr int HC = H * C;
  constexpr int CPL = HC / 64;
  constexpr int GROUP = C / CPL;
  const int n = (blockIdx.x * blockDim.x + threadIdx.x) >> 6;
  const int lane = threadIdx.x & 63;
  if (n >= NNODES) return;
  const int s0 = off[n], s1 = off[n + 1];

  float xrr[CPL], atr[CPL];
  if constexpr (CPL == 8) {
    unpack8(*(const int4*)(xr + (size_t)n * HC + lane * 8), xrr);
    const float4 a0 = *(const float4*)(att + lane * 8);
    const float4 a1 = *(const float4*)(att + lane * 8 + 4);
    atr[0] = a0.x; atr[1] = a0.y; atr[2] = a0.z; atr[3] = a0.w;
    atr[4] = a1.x; atr[5] = a1.y; atr[6] = a1.z; atr[7] = a1.w;
  } else {
    xrr[0] = b2f(xr[(size_t)n * HC + lane]);
    atr[0] = att[lane];
  }

  float m = -1e30f, s = 0.f;
  float acc[CPL] = {};

  int4 vnext = make_int4(0, 0, 0, 0);
  ushort_t unext = 0;
  if (s0 < s1) {
    const int srcn = ei[eids[s0]];
    if constexpr (CPL == 8) vnext = *(const int4*)(xl + (size_t)srcn * HC + lane * 8);
    else                    unext = xl[(size_t)srcn * HC + lane];
  }
  for (int i = s0; i < s1; ++i) {
    int4 vcur = vnext; ushort_t ucur = unext;
    if (i + 1 < s1) {
      const int srcn = ei[eids[i + 1]];
      if constexpr (CPL == 8) vnext = *(const int4*)(xl + (size_t)srcn * HC + lane * 8);
      else                    unext = xl[(size_t)srcn * HC + lane];
    }
    float zl[CPL];
    if constexpr (CPL == 8) unpack8(vcur, zl);
    else zl[0] = b2f(ucur);
    float e = 0.f;
    #pragma unroll
    for (int c = 0; c < CPL; ++c) {
      float z = zl[c] + xrr[c];
      z = (z > 0.f) ? z : 0.2f * z;
      e += z * atr[c];
    }
    #pragma unroll
    for (int o = 1; o < GROUP; o <<= 1)
      e += __shfl_xor(e, o, 64);
    if (e > m) {
      const float scale = __expf(m - e);
      s *= scale;
      #pragma unroll
      for (int c = 0; c < CPL; ++c) acc[c] *= scale;
      m = e;
    }
    const float w = __expf(e - m);
    s += w;
    #pragma unroll
    for (int c = 0; c < CPL; ++c) acc[c] += w * zl[c];
  }
  const float inv = 1.f / (s + 1e-16f);
  TO* po = out + (size_t)n * HC + lane * CPL;
  #pragma unroll
  for (int c = 0; c < CPL; ++c) {
    float v = acc[c] * inv + bias[lane * CPL + c];
    if (ELU) v = v > 0.f ? v : (__expf(v) - 1.f);
    stf(&po[c], v);
  }
}

// ---------- emergency: report ws_size via absmax ----------
__global__ void report_ws(float* __restrict__ out, float v) { out[0] = v; }

// ---------- orchestration ----------
extern "C" void kernel_launch(void* const* d_in, const int* in_sizes, int n_in,
                              void* d_out, int out_size, void* d_ws, size_t ws_size,
                              hipStream_t stream) {
  const float* x  = (const float*)d_in[0];
  const int*   ei = (const int*)d_in[1];
  float* out = (float*)d_out;
  char* ws = (char*)d_ws;

  // layout (bytes), all 16B-aligned
  ushort_t* hbuf = (ushort_t*)(ws);                   // N*512 bf16  51,200,000
  ushort_t* xlb  = (ushort_t*)(ws + 51200000ull);     // N*512 bf16  51,200,000
  ushort_t* xrb  = (ushort_t*)(ws + 102400000ull);    // N*512 bf16  51,200,000
  ushort_t* xb   = (ushort_t*)(ws + 153600000ull);    // N*128 bf16  12,800,000
  ushort_t* WtLR = (ushort_t*)(ws + 166400000ull);    // 2*512*512*2 = 2,097,152
  int* bsum  = (int*)(ws + 168500000ull);
  int* bpref = (int*)(ws + 168501024ull);
  int* coff  = (int*)(ws + 168600000ull);             // N+1
  int* cpos  = (int*)(ws + 168800008ull);             // N
  int* cdeg  = (int*)(ws + 169000012ull);             // N
  int* eids  = (int*)(ws + 169200016ull);             // E -> end 170,000,016

  if (ws_size < 170000016ull) {
    report_ws<<<1, 1, 0, stream>>>(out, (float)ws_size);
    return;
  }

  cast_x<<<(NNODES * 128 / 8 + 255) / 256, 256, 0, stream>>>(x, xb, NNODES * 128 / 8);
  csr_zero<<<(NNODES + 255) / 256, 256, 0, stream>>>(cdeg);
  csr_hist<<<(NEDGES + 255) / 256, 256, 0, stream>>>(ei, cdeg);
  scan_k1<<<SCAN_BLK, SCAN_TPB, 0, stream>>>(cdeg, bsum);
  scan_k2<<<1, 64, 0, stream>>>(bsum, bpref, coff);
  scan_k3<<<SCAN_BLK, SCAN_TPB, 0, stream>>>(cdeg, bpref, coff, cpos);
  csr_fill<<<(NEDGES + 255) / 256, 256, 0, stream>>>(ei, cpos, eids);

  const int ngrid = (NNODES * 64 + 255) / 256;
  const int nrp = (NNODES + 127) / 128;               // 391 row panels

  for (int layer = 0; layer < 4; ++layer) {
    const int base = 2 + layer * 6;
    const float* Wl  = (const float*)d_in[base + 0];
    const float* bl  = (const float*)d_in[base + 1];
    const float* Wr  = (const float*)d_in[base + 2];
    const float* br  = (const float*)d_in[base + 3];
    const float* att = (const float*)d_in[base + 4];
    const float* b   = (const float*)d_in[base + 5];

    const ushort_t* A = (layer == 0) ? xb : hbuf;
    const int K  = (layer == 0) ? 128 : 512;
    const int Mo = (layer == 3) ? 64 : 512;
    const int ncb = 2 * Mo / 128;                     // col blocks

    wt_prep2<<<(2 * K * Mo + 255) / 256, 256, 0, stream>>>(Wl, Wr, WtLR, K, Mo);

    gemm2_mfma<<<ncb * nrp, 256, 0, stream>>>(A, WtLR, bl, br, xlb, xrb,
                                              NNODES, K, Mo, ncb);

    if (layer < 3) {
      csr_fused<4, 128, true, ushort_t><<<ngrid, 256, 0, stream>>>(
          coff, eids, ei, xlb, xrb, att, b, hbuf);
    } else {
      csr_fused<1, 64, false, float><<<ngrid, 256, 0, stream>>>(
          coff, eids, ei, xlb, xrb, att, b, out);
    }
  }
}

// Round 10
// 572.385 us; speedup vs baseline: 1.1017x; 1.1017x over previous
//
#include <hip/hip_runtime.h>
#include <math.h>

#define NNODES 50000
#define NEDGES 200000

typedef unsigned short ushort_t;
using frag8 = __attribute__((ext_vector_type(8))) short;   // 8 x bf16
using facc4 = __attribute__((ext_vector_type(4))) float;   // 4 x f32

// ---------- bf16 helpers (bit-level, RNE) ----------
static __device__ __forceinline__ ushort_t f2b(float f) {
  union { float f; unsigned u; } v; v.f = f;
  unsigned r = v.u + 0x7FFFu + ((v.u >> 16) & 1u);
  return (ushort_t)(r >> 16);
}
static __device__ __forceinline__ float b2f(unsigned hi) {
  return __uint_as_float(hi << 16);
}
static __device__ __forceinline__ void unpack8(const int4 v, float* f) {
  f[0] = b2f((unsigned)v.x & 0xFFFFu); f[1] = b2f((unsigned)v.x >> 16);
  f[2] = b2f((unsigned)v.y & 0xFFFFu); f[3] = b2f((unsigned)v.y >> 16);
  f[4] = b2f((unsigned)v.z & 0xFFFFu); f[5] = b2f((unsigned)v.z >> 16);
  f[6] = b2f((unsigned)v.w & 0xFFFFu); f[7] = b2f((unsigned)v.w >> 16);
}
static __device__ __forceinline__ void stf(float* p, float v) { *p = v; }
static __device__ __forceinline__ void stf(ushort_t* p, float v) { *p = f2b(v); }

// ---------- cast x (fp32) -> bf16, 8 elems/thread ----------
__global__ void cast_x(const float* __restrict__ x, ushort_t* __restrict__ xb, int total8) {
  int t = blockIdx.x * 256 + threadIdx.x;
  if (t >= total8) return;
  const float4* p = (const float4*)(x + (size_t)t * 8);
  float4 a = p[0], b = p[1];
  int4 w = make_int4(
      (int)((unsigned)f2b(a.x) | ((unsigned)f2b(a.y) << 16)),
      (int)((unsigned)f2b(a.z) | ((unsigned)f2b(a.w) << 16)),
      (int)((unsigned)f2b(b.x) | ((unsigned)f2b(b.y) << 16)),
      (int)((unsigned)f2b(b.z) | ((unsigned)f2b(b.w) << 16)));
  *(int4*)(xb + (size_t)t * 8) = w;
}

// ---------- weight transpose + cast (L and R into one buffer) ----------
__global__ void wt_prep2(const float* __restrict__ Wl, const float* __restrict__ Wr,
                         ushort_t* __restrict__ WtLR, int K, int Mo) {
  int t = blockIdx.x * 256 + threadIdx.x;
  const int tot = K * Mo;
  if (t >= 2 * tot) return;
  const float* W = (t < tot) ? Wl : Wr;
  int u = (t < tot) ? t : t - tot;
  int c = u / K, k = u - c * K;
  WtLR[t] = f2b(W[(size_t)k * Mo + c]);
}

// ---------- fused MFMA GEMM: [xl|xr][N,Mo](bf16) = A[N,K](bf16) * WtLR + bias ----------
// Round-8 K-loop (reg-staged, BK=32) + halved Cl epilogue -> 17.9KB LDS union.
__global__ __launch_bounds__(256) void gemm2_mfma(
    const ushort_t* __restrict__ A, const ushort_t* __restrict__ WtLR,
    const float* __restrict__ bl, const float* __restrict__ br,
    ushort_t* __restrict__ xlb, ushort_t* __restrict__ xrb,
    int N, int K, int Mo, int ncb) {
  // union: Al(8KB)+Bl(8KB) = 16KB  /  Cl [64][140] = 17.9KB  -> 17920B total
  __shared__ __align__(16) char smem[17920];
  auto Al = reinterpret_cast<ushort_t(*)[128][8]>(smem);          // [4][128][8]
  auto Bl = reinterpret_cast<ushort_t(*)[128][8]>(smem + 8192);   // [4][128][8]
  auto Cl = reinterpret_cast<ushort_t(*)[140]>(smem);             // [64][140]

  // bijective XCD-chunked swizzle
  const int nwg = gridDim.x;
  const int q = nwg >> 3, r = nwg & 7;
  const int xcd = blockIdx.x & 7, pos = blockIdx.x >> 3;
  const int orig = (xcd < r ? xcd * (q + 1) : r * (q + 1) + (xcd - r) * q) + pos;
  const int rp = orig / ncb, cb = orig - rp * ncb;
  const int brow = rp * 128;
  const int bcol = cb * 128;                 // within [0, 2*Mo)

  const int tid = threadIdx.x;
  const int w = tid >> 6, lane = tid & 63;
  const int wr = w >> 1, wc = w & 1;         // 2x2 waves
  const int l15 = lane & 15, l4 = lane >> 4;

  facc4 acc[4][4] = {};

  const int srow = tid >> 1;         // 0..127
  const int skb  = (tid & 1) * 2;    // kblock 0 or 2
  for (int k0 = 0; k0 < K; k0 += 32) {
    {
      const int grow = brow + srow;
      int4 a0, a1;
      if (grow < N) {
        const int4* pa = (const int4*)(A + (size_t)grow * K + k0 + skb * 8);
        a0 = pa[0]; a1 = pa[1];
      } else {
        a0 = a1 = make_int4(0, 0, 0, 0);
      }
      *(int4*)&Al[skb + 0][srow][0] = a0;
      *(int4*)&Al[skb + 1][srow][0] = a1;
      const int4* pb = (const int4*)(WtLR + (size_t)(bcol + srow) * K + k0 + skb * 8);
      int4 b0 = pb[0], b1 = pb[1];
      *(int4*)&Bl[skb + 0][srow][0] = b0;
      *(int4*)&Bl[skb + 1][srow][0] = b1;
    }
    __syncthreads();
    frag8 af[4], bfg[4];
    #pragma unroll
    for (int i = 0; i < 4; ++i)
      af[i] = *(const frag8*)&Al[l4][wr * 64 + i * 16 + l15][0];
    #pragma unroll
    for (int j = 0; j < 4; ++j)
      bfg[j] = *(const frag8*)&Bl[l4][wc * 64 + j * 16 + l15][0];
    #pragma unroll
    for (int i = 0; i < 4; ++i)
      #pragma unroll
      for (int j = 0; j < 4; ++j)
        acc[i][j] = __builtin_amdgcn_mfma_f32_16x16x32_bf16(af[i], bfg[j], acc[i][j], 0, 0, 0);
    __syncthreads();
  }

  // ---- epilogue: two 64-row halves through LDS, coalesced int4 writeout ----
  #pragma unroll
  for (int half = 0; half < 2; ++half) {
    if (wr == half) {
      #pragma unroll
      for (int j = 0; j < 4; ++j) {
        const int lcol = wc * 64 + j * 16 + l15;
        const int col2 = bcol + lcol;
        const float bv = (col2 < Mo) ? bl[col2] : br[col2 - Mo];
        #pragma unroll
        for (int i = 0; i < 4; ++i) {
          const int lrow = i * 16 + l4 * 4;
          #pragma unroll
          for (int rr = 0; rr < 4; ++rr)
            Cl[lrow + rr][lcol] = f2b(acc[i][j][rr] + bv);
        }
      }
    }
    __syncthreads();
    {
      const int row = tid >> 2, cq = tid & 3;
      const int grow = brow + half * 64 + row;
      if (grow < N) {
        const int colb = cq * 32;
        const int col2 = bcol + colb;          // side uniform per 32-col chunk
        const bool isL = col2 < Mo;
        ushort_t* dst = (isL ? xlb : xrb) + (size_t)grow * Mo + (isL ? col2 : col2 - Mo);
        #pragma unroll
        for (int k = 0; k < 4; ++k) {
          int4 v = *(const int4*)&Cl[row][colb + k * 8];
          *(int4*)(dst + k * 8) = v;
        }
      }
    }
    __syncthreads();
  }
}

// ---------- CSR build (by dst) ----------
__global__ void csr_zero(int* __restrict__ deg) {
  int t = blockIdx.x * blockDim.x + threadIdx.x;
  if (t < NNODES) deg[t] = 0;
}
__global__ void csr_hist(const int* __restrict__ ei, int* __restrict__ deg) {
  int e = blockIdx.x * blockDim.x + threadIdx.x;
  if (e >= NEDGES) return;
  atomicAdd(&deg[ei[NEDGES + e]], 1);
}

#define SCAN_TPB 256
#define SCAN_EPT 4
#define SCAN_CHUNK (SCAN_TPB * SCAN_EPT)                       // 1024
#define SCAN_BLK ((NNODES + SCAN_CHUNK - 1) / SCAN_CHUNK)      // 49

__global__ __launch_bounds__(SCAN_TPB) void scan_k1(const int* __restrict__ deg,
                                                    int* __restrict__ bsum) {
  __shared__ int sd[SCAN_TPB];
  const int tid = threadIdx.x;
  const int tbase = blockIdx.x * SCAN_CHUNK + tid * SCAN_EPT;
  int s = 0;
  #pragma unroll
  for (int j = 0; j < SCAN_EPT; ++j) {
    int idx = tbase + j;
    if (idx < NNODES) s += deg[idx];
  }
  sd[tid] = s;
  __syncthreads();
  for (int d = SCAN_TPB / 2; d > 0; d >>= 1) {
    if (tid < d) sd[tid] += sd[tid + d];
    __syncthreads();
  }
  if (tid == 0) bsum[blockIdx.x] = sd[0];
}

__global__ __launch_bounds__(64) void scan_k2(const int* __restrict__ bsum,
                                              int* __restrict__ bpref,
                                              int* __restrict__ off) {
  __shared__ int sd[64];
  const int tid = threadIdx.x;
  sd[tid] = (tid < SCAN_BLK) ? bsum[tid] : 0;
  __syncthreads();
  for (int d = 1; d < 64; d <<= 1) {
    int t = (tid >= d) ? sd[tid - d] : 0;
    __syncthreads();
    sd[tid] += t;
    __syncthreads();
  }
  if (tid < SCAN_BLK) bpref[tid] = (tid == 0) ? 0 : sd[tid - 1];
  if (tid == 0) off[NNODES] = NEDGES;
}

__global__ __launch_bounds__(SCAN_TPB) void scan_k3(const int* __restrict__ deg,
                                                    const int* __restrict__ bpref,
                                                    int* __restrict__ off,
                                                    int* __restrict__ pos) {
  __shared__ int sd[SCAN_TPB];
  const int tid = threadIdx.x;
  const int tbase = blockIdx.x * SCAN_CHUNK + tid * SCAN_EPT;
  int v[SCAN_EPT];
  int s = 0;
  #pragma unroll
  for (int j = 0; j < SCAN_EPT; ++j) {
    int idx = tbase + j;
    v[j] = (idx < NNODES) ? deg[idx] : 0;
    s += v[j];
  }
  sd[tid] = s;
  __syncthreads();
  for (int d = 1; d < SCAN_TPB; d <<= 1) {
    int t = (tid >= d) ? sd[tid - d] : 0;
    __syncthreads();
    sd[tid] += t;
    __syncthreads();
  }
  int run = bpref[blockIdx.x] + ((tid == 0) ? 0 : sd[tid - 1]);
  #pragma unroll
  for (int j = 0; j < SCAN_EPT; ++j) {
    int idx = tbase + j;
    if (idx < NNODES) { off[idx] = run; pos[idx] = run; run += v[j]; }
  }
}

__global__ void csr_fill(const int* __restrict__ ei, int* __restrict__ pos,
                         int* __restrict__ eids) {
  int e = blockIdx.x * blockDim.x + threadIdx.x;
  if (e >= NEDGES) return;
  int p = atomicAdd(&pos[ei[NEDGES + e]], 1);
  eids[p] = e;
}

// ---------- fused attention + online-softmax aggregation, one wave/node ----------
template<int H, int C, bool ELU, typename TO>
__global__ __launch_bounds__(256) void csr_fused(
    const int* __restrict__ off, const int* __restrict__ eids,
    const int* __restrict__ ei, const ushort_t* __restrict__ xl,
    const ushort_t* __restrict__ xr, const float* __restrict__ att,
    const float* __restrict__ bias, TO* __restrict__ out) {
  constexpr int HC = H * C;
  constexpr int CPL = HC / 64;
  constexpr int GROUP = C / CPL;
  const int n = (blockIdx.x * blockDim.x + threadIdx.x) >> 6;
  const int lane = threadIdx.x & 63;
  if (n >= NNODES) return;
  const int s0 = off[n], s1 = off[n + 1];

  float xrr[CPL], atr[CPL];
  if constexpr (CPL == 8) {
    unpack8(*(const int4*)(xr + (size_t)n * HC + lane * 8), xrr);
    const float4 a0 = *(const float4*)(att + lane * 8);
    const float4 a1 = *(const float4*)(att + lane * 8 + 4);
    atr[0] = a0.x; atr[1] = a0.y; atr[2] = a0.z; atr[3] = a0.w;
    atr[4] = a1.x; atr[5] = a1.y; atr[6] = a1.z; atr[7] = a1.w;
  } else {
    xrr[0] = b2f(xr[(size_t)n * HC + lane]);
    atr[0] = att[lane];
  }

  float m = -1e30f, s = 0.f;
  float acc[CPL] = {};

  int4 vnext = make_int4(0, 0, 0, 0);
  ushort_t unext = 0;
  if (s0 < s1) {
    const int srcn = ei[eids[s0]];
    if constexpr (CPL == 8) vnext = *(const int4*)(xl + (size_t)srcn * HC + lane * 8);
    else                    unext = xl[(size_t)srcn * HC + lane];
  }
  for (int i = s0; i < s1; ++i) {
    int4 vcur = vnext; ushort_t ucur = unext;
    if (i + 1 < s1) {
      const int srcn = ei[eids[i + 1]];
      if constexpr (CPL == 8) vnext = *(const int4*)(xl + (size_t)srcn * HC + lane * 8);
      else                    unext = xl[(size_t)srcn * HC + lane];
    }
    float zl[CPL];
    if constexpr (CPL == 8) unpack8(vcur, zl);
    else zl[0] = b2f(ucur);
    float e = 0.f;
    #pragma unroll
    for (int c = 0; c < CPL; ++c) {
      float z = zl[c] + xrr[c];
      z = (z > 0.f) ? z : 0.2f * z;
      e += z * atr[c];
    }
    #pragma unroll
    for (int o = 1; o < GROUP; o <<= 1)
      e += __shfl_xor(e, o, 64);
    if (e > m) {
      const float scale = __expf(m - e);
      s *= scale;
      #pragma unroll
      for (int c = 0; c < CPL; ++c) acc[c] *= scale;
      m = e;
    }
    const float w = __expf(e - m);
    s += w;
    #pragma unroll
    for (int c = 0; c < CPL; ++c) acc[c] += w * zl[c];
  }
  const float inv = 1.f / (s + 1e-16f);
  TO* po = out + (size_t)n * HC + lane * CPL;
  #pragma unroll
  for (int c = 0; c < CPL; ++c) {
    float v = acc[c] * inv + bias[lane * CPL + c];
    if (ELU) v = v > 0.f ? v : (__expf(v) - 1.f);
    stf(&po[c], v);
  }
}

// ---------- emergency: report ws_size via absmax ----------
__global__ void report_ws(float* __restrict__ out, float v) { out[0] = v; }

// ---------- orchestration ----------
extern "C" void kernel_launch(void* const* d_in, const int* in_sizes, int n_in,
                              void* d_out, int out_size, void* d_ws, size_t ws_size,
                              hipStream_t stream) {
  const float* x  = (const float*)d_in[0];
  const int*   ei = (const int*)d_in[1];
  float* out = (float*)d_out;
  char* ws = (char*)d_ws;

  // layout (bytes), all 16B-aligned
  ushort_t* hbuf = (ushort_t*)(ws);                   // N*512 bf16  51,200,000
  ushort_t* xlb  = (ushort_t*)(ws + 51200000ull);     // N*512 bf16  51,200,000
  ushort_t* xrb  = (ushort_t*)(ws + 102400000ull);    // N*512 bf16  51,200,000
  ushort_t* xb   = (ushort_t*)(ws + 153600000ull);    // N*128 bf16  12,800,000
  ushort_t* WtLR = (ushort_t*)(ws + 166400000ull);    // 2*512*512*2 = 2,097,152
  int* bsum  = (int*)(ws + 168500000ull);
  int* bpref = (int*)(ws + 168501024ull);
  int* coff  = (int*)(ws + 168600000ull);             // N+1
  int* cpos  = (int*)(ws + 168800008ull);             // N
  int* cdeg  = (int*)(ws + 169000012ull);             // N
  int* eids  = (int*)(ws + 169200016ull);             // E -> end 170,000,016

  if (ws_size < 170000016ull) {
    report_ws<<<1, 1, 0, stream>>>(out, (float)ws_size);
    return;
  }

  cast_x<<<(NNODES * 128 / 8 + 255) / 256, 256, 0, stream>>>(x, xb, NNODES * 128 / 8);
  csr_zero<<<(NNODES + 255) / 256, 256, 0, stream>>>(cdeg);
  csr_hist<<<(NEDGES + 255) / 256, 256, 0, stream>>>(ei, cdeg);
  scan_k1<<<SCAN_BLK, SCAN_TPB, 0, stream>>>(cdeg, bsum);
  scan_k2<<<1, 64, 0, stream>>>(bsum, bpref, coff);
  scan_k3<<<SCAN_BLK, SCAN_TPB, 0, stream>>>(cdeg, bpref, coff, cpos);
  csr_fill<<<(NEDGES + 255) / 256, 256, 0, stream>>>(ei, cpos, eids);

  const int ngrid = (NNODES * 64 + 255) / 256;
  const int nrp = (NNODES + 127) / 128;               // 391 row panels

  for (int layer = 0; layer < 4; ++layer) {
    const int base = 2 + layer * 6;
    const float* Wl  = (const float*)d_in[base + 0];
    const float* bl  = (const float*)d_in[base + 1];
    const float* Wr  = (const float*)d_in[base + 2];
    const float* br  = (const float*)d_in[base + 3];
    const float* att = (const float*)d_in[base + 4];
    const float* b   = (const float*)d_in[base + 5];

    const ushort_t* A = (layer == 0) ? xb : hbuf;
    const int K  = (layer == 0) ? 128 : 512;
    const int Mo = (layer == 3) ? 64 : 512;
    const int ncb = 2 * Mo / 128;                     // col blocks

    wt_prep2<<<(2 * K * Mo + 255) / 256, 256, 0, stream>>>(Wl, Wr, WtLR, K, Mo);

    gemm2_mfma<<<ncb * nrp, 256, 0, stream>>>(A, WtLR, bl, br, xlb, xrb,
                                              NNODES, K, Mo, ncb);

    if (layer < 3) {
      csr_fused<4, 128, true, ushort_t><<<ngrid, 256, 0, stream>>>(
          coff, eids, ei, xlb, xrb, att, b, hbuf);
    } else {
      csr_fused<1, 64, false, float><<<ngrid, 256, 0, stream>>>(
          coff, eids, ei, xlb, xrb, att, b, out);
    }
  }
}